// Round 3
// baseline (272.362 us; speedup 1.0000x reference)
//
#include <hip/hip_runtime.h>
#include <hip/hip_bf16.h>

typedef __attribute__((ext_vector_type(8))) __bf16 bf16x8;
typedef __attribute__((ext_vector_type(8))) short short8;
typedef __attribute__((ext_vector_type(4))) float f32x4;
typedef __attribute__((ext_vector_type(4))) unsigned int uint4v;
typedef __attribute__((ext_vector_type(2))) unsigned int uint2v;

#define KS 72
#define LOG2E 1.44269504088896340736f

// pack two fp32 -> two bf16 (lo in low short), round-half-up
__device__ __forceinline__ unsigned pack2bf(float lo, float hi) {
    unsigned a = __builtin_bit_cast(unsigned, lo) + 0x8000u;
    unsigned b = __builtin_bit_cast(unsigned, hi) + 0x8000u;
    return __builtin_amdgcn_perm(b, a, 0x07060302u);
}

__device__ __forceinline__ bf16x8 ldfrag(const short* p) {
    short8 s = *reinterpret_cast<const short8*>(p);
    return __builtin_bit_cast(bf16x8, s);
}

// S^T formulation: QK MFMA computes S^T[key][q] (A=K, B=Q); PV computes
// O^T[d][q] (A=V^T, B=P^T). Lane owns one q row (q = lane&15).
// R3: VALU/chain cuts on the R2 pipeline --
//  - enc tiles (kt=0,1 exactly, ENC=128) use direct enc addressing; video
//    tiles use ONE role-unified pointer advanced by += 64 rows/tile (no
//    per-tile 64-bit pointer rebuilds, no enc/video selects in the loop)
//  - main loop is branch-free full-tile (nsub==4); partial last tile split out
//  - defer-max (T13, THR=8 log2): skip alpha/rescale when wave max growth <= 8
//  - s_setprio(1) around MFMA clusters (T5): 3 independent blocks/CU
//  - waves with all q-rows >= seqlen skip compute (still stage + barrier)
__global__ __launch_bounds__(512, 6) void vfa_kernel(
    const float* __restrict__ qv, const float* __restrict__ kv, const float* __restrict__ vv,
    const float* __restrict__ eq, const float* __restrict__ ek, const float* __restrict__ ev,
    const float* __restrict__ scale_p, float* __restrict__ out)
{
    constexpr int H = 16, Dh = 64, ENC = 128, SV = 1536;
    constexpr int ROWF = H*Dh;           // floats per token row = 1024
    constexpr int TILEF = 64*ROWF;       // floats per 64-row tile = 65536
    constexpr int SS_CUM[9] = {0,144,272,384,480,560,640,704,768};
    constexpr int SEQL[8] = {1152,1008,864,720,640,560,480,400};
    constexpr int QTN[8]  = {9,8,7,6,5,5,4,4};          // ceil(seqlen/128)
    constexpr int OB[8]   = {2080,4096,3232,5104,0,1120,640,1680};
    constexpr int BB[8]   = {1,5,3,7,0,4,2,6};
    constexpr int ISUM[8] = {512,512,512,512,0,0,0,0};

    __shared__ __align__(16) short smem[4*64*KS];   // 2 x {K[64][KS] | V^T[64][KS]}

    const int bid = blockIdx.x;
    int ss = 0;
    #pragma unroll
    for (int i = 1; i < 8; ++i) ss += (bid >= SS_CUM[i]) ? 1 : 0;
    const int seqlen   = SEQL[ss];
    const int nqt      = QTN[ss];
    const int b        = BB[ss];
    const int isum     = ISUM[ss];
    const int out_base = OB[ss];
    const int local    = bid - SS_CUM[ss];
    const int head     = local / nqt;
    const int qt       = local - head * nqt;

    const int tid  = threadIdx.x;
    const int wave = tid >> 6;          // 0..7, wave owns q rows qt*128 + wave*16 + l15
    const int lane = tid & 63;
    const int quad = lane >> 4;
    const int l15  = lane & 15;

    const float qmul = scale_p[0] * LOG2E;

    // ---- Q fragments (B-operand layout: n=l15, k=quad*8+j) ----
    const int qrow = qt*128 + wave*16 + l15;   // always < padded Lc (checked per ss)
    const float* qrp;
    if (qrow < ENC) qrp = eq + ((b*ENC + qrow)*H + head)*Dh;
    else            qrp = qv + (((b*SV + isum) + (qrow - ENC))*H + head)*Dh;
    bf16x8 qfrag[2];
    #pragma unroll
    for (int f = 0; f < 2; ++f) {
        const float* p = qrp + f*32 + quad*8;
        f32x4 a = *reinterpret_cast<const f32x4*>(p);
        f32x4 c = *reinterpret_cast<const f32x4*>(p + 4);
        uint4v u;
        u[0] = pack2bf(a[0]*qmul, a[1]*qmul);
        u[1] = pack2bf(a[2]*qmul, a[3]*qmul);
        u[2] = pack2bf(c[0]*qmul, c[1]*qmul);
        u[3] = pack2bf(c[2]*qmul, c[3]*qmul);
        qfrag[f] = __builtin_bit_cast(bf16x8, u);
    }

    f32x4 acc[4];                    // O^T: acc[dt] row d = dt*16+quad*4+reg, col q=l15
    #pragma unroll
    for (int dt = 0; dt < 4; ++dt) acc[dt] = {0.f,0.f,0.f,0.f};
    float m_s = -INFINITY, l_s = 0.f;   // per-lane scalars (q = l15)

    // staging roles: waves 0-3 stage K, waves 4-7 stage V (each thread 16 elems)
    const int t2  = tid & 255;
    const int klk = t2 >> 2;            // K: key row 0..63
    const int kd  = (t2 & 3) * 16;      // K: d base
    const int vk0 = (t2 & 15) * 4;      // V: key base (4 consecutive keys)
    const int vd0 = (t2 >> 4) * 4;      // V: d base (4 consecutive d)
    const bool krole = (tid < 256);

    // role-unified staging pointers: K-role reads 1 row x 64 d from (klk, kd);
    // V-role reads 4 rows x 4 d from (vk0.., vd0). Same 4-load shape, offsets differ.
    const float* encP = krole
        ? ek + ((size_t)(b*ENC + klk)*H + head)*Dh + kd
        : ev + ((size_t)(b*ENC + vk0)*H + head)*Dh + vd0;
    const float* vidP = krole
        ? kv + ((size_t)((b*SV + isum) + klk)*H + head)*Dh + kd
        : vv + ((size_t)((b*SV + isum) + vk0)*H + head)*Dh + vd0;
    const int o1 = krole ? 4 : ROWF;
    const int o2 = krole ? 8 : 2*ROWF;
    const int o3 = krole ? 12 : 3*ROWF;

    f32x4 ld0, ld1, ld2, ld3;           // prefetch registers (live across compute)

    auto issue = [&](const float* base) {
        ld0 = *reinterpret_cast<const f32x4*>(base);
        ld1 = *reinterpret_cast<const f32x4*>(base + o1);
        ld2 = *reinterpret_cast<const f32x4*>(base + o2);
        ld3 = *reinterpret_cast<const f32x4*>(base + o3);
    };

    auto write_tile = [&](short* kb, short* vb) {
        if (krole) {
            // K row-major bf16, 2x ds_write_b128
            uint4v kp;
            kp[0] = pack2bf(ld0[0], ld0[1]);
            kp[1] = pack2bf(ld0[2], ld0[3]);
            kp[2] = pack2bf(ld1[0], ld1[1]);
            kp[3] = pack2bf(ld1[2], ld1[3]);
            *reinterpret_cast<uint4v*>(&kb[klk*KS + kd]) = kp;
            kp[0] = pack2bf(ld2[0], ld2[1]);
            kp[1] = pack2bf(ld2[2], ld2[3]);
            kp[2] = pack2bf(ld3[0], ld3[1]);
            kp[3] = pack2bf(ld3[2], ld3[3]);
            *reinterpret_cast<uint4v*>(&kb[klk*KS + kd + 8]) = kp;
        } else {
            // V^T: register 4x4 transpose, 4x ds_write_b64
            #pragma unroll
            for (int j = 0; j < 4; ++j) {        // d = vd0 + j
                uint2v w;
                w[0] = pack2bf(ld0[j], ld1[j]);   // keys vk0, vk0+1
                w[1] = pack2bf(ld2[j], ld3[j]);   // keys vk0+2, vk0+3
                *reinterpret_cast<uint2v*>(&vb[(vd0 + j)*KS + vk0]) = w;
            }
        }
    };

    const int nkt = (seqlen + 63) >> 6;
    const int nsub_last = ((seqlen & 63) ? ((seqlen & 63) >> 4) : 4);
    const int nfull = (nsub_last == 4) ? nkt : nkt - 1;
    const bool active_q = (qt*128 + wave*16) < seqlen;   // wave has any valid q row
    const int src_base = l15 + ((quad & 1) << 5);        // bpermute source base lane

    // ---- full tile: nsub==4, branch-free, defer-max, setprio ----
    auto compute_full = [&](const short* kb, const short* vb) {
        f32x4 sv[4];
        __builtin_amdgcn_s_setprio(1);
        #pragma unroll
        for (int sub = 0; sub < 4; ++sub) {
            const short* kr0 = &kb[(sub*16 + l15)*KS + quad*8];
            f32x4 t = {0.f,0.f,0.f,0.f};
            t = __builtin_amdgcn_mfma_f32_16x16x32_bf16(ldfrag(kr0),      qfrag[0], t, 0,0,0);
            t = __builtin_amdgcn_mfma_f32_16x16x32_bf16(ldfrag(kr0 + 32), qfrag[1], t, 0,0,0);
            sv[sub] = t;
        }
        __builtin_amdgcn_s_setprio(0);

        // wave-wide row max (q = l15)
        float m0 = fmaxf(fmaxf(sv[0][0], sv[0][1]), fmaxf(sv[0][2], sv[0][3]));
        float m1 = fmaxf(fmaxf(sv[1][0], sv[1][1]), fmaxf(sv[1][2], sv[1][3]));
        float m2 = fmaxf(fmaxf(sv[2][0], sv[2][1]), fmaxf(sv[2][2], sv[2][3]));
        float m3 = fmaxf(fmaxf(sv[3][0], sv[3][1]), fmaxf(sv[3][2], sv[3][3]));
        float mx = fmaxf(fmaxf(m0, m1), fmaxf(m2, m3));
        mx = fmaxf(mx, __shfl_xor(mx, 16, 64));
        mx = fmaxf(mx, __shfl_xor(mx, 32, 64));

        // defer-max: only rescale when max grew by > 8 (log2 domain) somewhere
        if (__ballot(mx > m_s + 8.f)) {
            const float mn = fmaxf(m_s, mx);
            const float alpha = __builtin_amdgcn_exp2f(m_s - mn);
            #pragma unroll
            for (int dt = 0; dt < 4; ++dt) acc[dt] *= alpha;
            l_s *= alpha;
            m_s = mn;
        }

        float rs = 0.f;
        unsigned pk[4][2];
        #pragma unroll
        for (int sub = 0; sub < 4; ++sub) {
            float p0 = __builtin_amdgcn_exp2f(sv[sub][0] - m_s);
            float p1 = __builtin_amdgcn_exp2f(sv[sub][1] - m_s);
            float p2 = __builtin_amdgcn_exp2f(sv[sub][2] - m_s);
            float p3 = __builtin_amdgcn_exp2f(sv[sub][3] - m_s);
            rs += (p0 + p1) + (p2 + p3);
            pk[sub][0] = pack2bf(p0, p1);
            pk[sub][1] = pack2bf(p2, p3);
        }
        rs += __shfl_xor(rs, 16, 64);
        rs += __shfl_xor(rs, 32, 64);
        l_s += rs;

        #pragma unroll
        for (int kstep = 0; kstep < 2; ++kstep) {
            uint4v pf;
            #pragma unroll
            for (int p = 0; p < 4; ++p) {
                const int sl = src_base + ((p >> 1) << 4);
                int va = __shfl((int)pk[kstep*2 + 0][p & 1], sl, 64);
                int vb2 = __shfl((int)pk[kstep*2 + 1][p & 1], sl, 64);
                pf[p] = (quad & 2) ? (unsigned)vb2 : (unsigned)va;
            }
            bf16x8 pfr = __builtin_bit_cast(bf16x8, pf);
            __builtin_amdgcn_s_setprio(1);
            #pragma unroll
            for (int dt = 0; dt < 4; ++dt) {
                bf16x8 vfr = ldfrag(&vb[(dt*16 + l15)*KS + kstep*32 + quad*8]);
                acc[dt] = __builtin_amdgcn_mfma_f32_16x16x32_bf16(vfr, pfr, acc[dt], 0,0,0);
            }
            __builtin_amdgcn_s_setprio(0);
        }
    };

    // ---- partial last tile: masked subs (runs at most once per block) ----
    auto compute_partial = [&](const short* kb, const short* vb) {
        const int nsub = nsub_last;
        float s[4][4];
        #pragma unroll
        for (int sub = 0; sub < 4; ++sub) {
            if (sub < nsub) {
                const short* kr0 = &kb[(sub*16 + l15)*KS + quad*8];
                f32x4 t = {0.f,0.f,0.f,0.f};
                t = __builtin_amdgcn_mfma_f32_16x16x32_bf16(ldfrag(kr0),      qfrag[0], t, 0,0,0);
                t = __builtin_amdgcn_mfma_f32_16x16x32_bf16(ldfrag(kr0 + 32), qfrag[1], t, 0,0,0);
                #pragma unroll
                for (int r = 0; r < 4; ++r) s[sub][r] = t[r];
            } else {
                #pragma unroll
                for (int r = 0; r < 4; ++r) s[sub][r] = -INFINITY;
            }
        }
        float mx = s[0][0];
        #pragma unroll
        for (int sub = 0; sub < 4; ++sub)
            #pragma unroll
            for (int r = 0; r < 4; ++r) mx = fmaxf(mx, s[sub][r]);
        mx = fmaxf(mx, __shfl_xor(mx, 16, 64));
        mx = fmaxf(mx, __shfl_xor(mx, 32, 64));
        const float mn = fmaxf(m_s, mx);
        const float alpha = __builtin_amdgcn_exp2f(m_s - mn);
        m_s = mn;
        #pragma unroll
        for (int dt = 0; dt < 4; ++dt) acc[dt] *= alpha;

        float rs = 0.f;
        unsigned pk[4][2];
        #pragma unroll
        for (int sub = 0; sub < 4; ++sub) {
            float p0 = __builtin_amdgcn_exp2f(s[sub][0] - mn);
            float p1 = __builtin_amdgcn_exp2f(s[sub][1] - mn);
            float p2 = __builtin_amdgcn_exp2f(s[sub][2] - mn);
            float p3 = __builtin_amdgcn_exp2f(s[sub][3] - mn);
            rs += (p0 + p1) + (p2 + p3);
            pk[sub][0] = pack2bf(p0, p1);
            pk[sub][1] = pack2bf(p2, p3);
        }
        rs += __shfl_xor(rs, 16, 64);
        rs += __shfl_xor(rs, 32, 64);
        l_s = l_s * alpha + rs;

        #pragma unroll
        for (int kstep = 0; kstep < 2; ++kstep) {
            if (kstep == 0 || nsub > 2) {
                uint4v pf;
                #pragma unroll
                for (int p = 0; p < 4; ++p) {
                    const int sl = src_base + ((p >> 1) << 4);
                    int va = __shfl((int)pk[kstep*2 + 0][p & 1], sl, 64);
                    int vb2 = __shfl((int)pk[kstep*2 + 1][p & 1], sl, 64);
                    pf[p] = (quad & 2) ? (unsigned)vb2 : (unsigned)va;
                }
                bf16x8 pfr = __builtin_bit_cast(bf16x8, pf);
                #pragma unroll
                for (int dt = 0; dt < 4; ++dt) {
                    bf16x8 vfr = ldfrag(&vb[(dt*16 + l15)*KS + kstep*32 + quad*8]);
                    acc[dt] = __builtin_amdgcn_mfma_f32_16x16x32_bf16(vfr, pfr, acc[dt], 0,0,0);
                }
            }
        }
    };

    // ---- pipelined k-loop: tiles 0,1 = encoder exactly; >=2 = video ----
    issue(encP);
    for (int t = 0; t < nkt; ++t) {
        short* kb = smem + (t & 1) * (2*64*KS);
        short* vb = kb + 64*KS;

        write_tile(kb, vb);                 // waits vmcnt on ld* (compiler)
        const int nx = t + 1;
        if (nx < nkt) {
            if (nx == 1) issue(encP + TILEF);
            else { issue(vidP); vidP += TILEF; }
        }

        asm volatile("s_waitcnt lgkmcnt(0)" ::: "memory");  // ds_writes visible
        __builtin_amdgcn_s_barrier();                        // no vmcnt drain
        __builtin_amdgcn_sched_barrier(0);

        if (active_q) {
            if (t < nfull) compute_full(kb, vb);
            else           compute_partial(kb, vb);
        }
    }

    // ---- epilogue: normalize, transpose via LDS (two 64-row passes), coalesced f32 store ----
    __syncthreads();                       // all waves done reading K/V buffers
    float* tbuf = reinterpret_cast<float*>(smem);   // [64][68] f32 = 17408 B
    const float inv = 1.0f / l_s;
    const int rowl = tid >> 3;             // 0..63
    const int colb = (tid & 7) * 8;        // 0..56
    #pragma unroll
    for (int p = 0; p < 2; ++p) {
        if (p) __syncthreads();            // previous pass's reads done before overwrite
        if ((wave >> 2) == p) {            // waves 0-3 own rows 0-63; waves 4-7 rows 64-127
            #pragma unroll
            for (int dt = 0; dt < 4; ++dt) {
                f32x4 t = acc[dt] * inv;
                *reinterpret_cast<f32x4*>(&tbuf[((wave & 3)*16 + l15)*68 + dt*16 + quad*4]) = t;
            }
        }
        __syncthreads();
        const int grow = qt*128 + p*64 + rowl;
        if (grow < seqlen) {
            float* orow = out + (size_t)(out_base + grow)*(H*Dh) + head*Dh + colb;
            const float* trow = tbuf + rowl*68 + colb;
            *reinterpret_cast<float4*>(orow)     = *reinterpret_cast<const float4*>(trow);
            *reinterpret_cast<float4*>(orow + 4) = *reinterpret_cast<const float4*>(trow + 4);
        }
    }
}

extern "C" void kernel_launch(void* const* d_in, const int* in_sizes, int n_in,
                              void* d_out, int out_size, void* d_ws, size_t ws_size,
                              hipStream_t stream) {
    const float* q     = (const float*)d_in[0];
    const float* k     = (const float*)d_in[1];
    const float* v     = (const float*)d_in[2];
    const float* eq    = (const float*)d_in[3];
    const float* ek    = (const float*)d_in[4];
    const float* ev    = (const float*)d_in[5];
    const float* scale = (const float*)d_in[11];
    float* out = (float*)d_out;

    vfa_kernel<<<dim3(768), dim3(512), 0, stream>>>(q, k, v, eq, ek, ev, scale, out);
}

// Round 4
// 215.404 us; speedup vs baseline: 1.2644x; 1.2644x over previous
//
#include <hip/hip_runtime.h>
#include <hip/hip_bf16.h>

typedef __attribute__((ext_vector_type(8))) __bf16 bf16x8;
typedef __attribute__((ext_vector_type(8))) short short8;
typedef __attribute__((ext_vector_type(4))) float f32x4;
typedef __attribute__((ext_vector_type(4))) unsigned int uint4v;
typedef __attribute__((ext_vector_type(2))) unsigned int uint2v;

#define KS 72
#define LOG2E 1.44269504088896340736f

// pack two fp32 -> two bf16 (lo in low short), round-half-up
__device__ __forceinline__ unsigned pack2bf(float lo, float hi) {
    unsigned a = __builtin_bit_cast(unsigned, lo) + 0x8000u;
    unsigned b = __builtin_bit_cast(unsigned, hi) + 0x8000u;
    return __builtin_amdgcn_perm(b, a, 0x07060302u);
}

__device__ __forceinline__ bf16x8 ldfrag(const short* p) {
    short8 s = *reinterpret_cast<const short8*>(p);
    return __builtin_bit_cast(bf16x8, s);
}

// S^T formulation: QK MFMA computes S^T[key][q] (A=K, B=Q); PV computes
// O^T[d][q] (A=V^T, B=P^T). Lane owns one q row (q = lane&15).
// R4 = R2 pipeline (single compute body -- R3's duplicated bodies spilled
// to scratch: symmetric +112MB FETCH/WRITE) + register-lean VALU cuts:
//  - incremental staging pointers (enc tiles are exactly kt=0,1; video
//    pointer advances += TILEF per tile; no per-tile 64-bit rebuilds)
//  - defer-max (T13) as a wave-uniform skip INSIDE the single body
//  - s_setprio(1) around MFMA clusters (T5)
//  - waves with all q-rows >= seqlen skip compute (stage + barrier only)
__global__ __launch_bounds__(512, 6) void vfa_kernel(
    const float* __restrict__ qv, const float* __restrict__ kv, const float* __restrict__ vv,
    const float* __restrict__ eq, const float* __restrict__ ek, const float* __restrict__ ev,
    const float* __restrict__ scale_p, float* __restrict__ out)
{
    constexpr int H = 16, Dh = 64, ENC = 128, SV = 1536;
    constexpr int ROWF = H*Dh;           // floats per token row = 1024
    constexpr int TILEF = 64*ROWF;       // floats per 64-row tile = 65536
    constexpr int SS_CUM[9] = {0,144,272,384,480,560,640,704,768};
    constexpr int SEQL[8] = {1152,1008,864,720,640,560,480,400};
    constexpr int QTN[8]  = {9,8,7,6,5,5,4,4};          // ceil(seqlen/128)
    constexpr int OB[8]   = {2080,4096,3232,5104,0,1120,640,1680};
    constexpr int BB[8]   = {1,5,3,7,0,4,2,6};
    constexpr int ISUM[8] = {512,512,512,512,0,0,0,0};

    __shared__ __align__(16) short smem[4*64*KS];   // 2 x {K[64][KS] | V^T[64][KS]}

    const int bid = blockIdx.x;
    int ss = 0;
    #pragma unroll
    for (int i = 1; i < 8; ++i) ss += (bid >= SS_CUM[i]) ? 1 : 0;
    const int seqlen   = SEQL[ss];
    const int nqt      = QTN[ss];
    const int b        = BB[ss];
    const int isum     = ISUM[ss];
    const int out_base = OB[ss];
    const int local    = bid - SS_CUM[ss];
    const int head     = local / nqt;
    const int qt       = local - head * nqt;

    const int tid  = threadIdx.x;
    const int wave = tid >> 6;          // 0..7, wave owns q rows qt*128 + wave*16 + l15
    const int lane = tid & 63;
    const int quad = lane >> 4;
    const int l15  = lane & 15;

    const float qmul = scale_p[0] * LOG2E;

    // ---- Q fragments (B-operand layout: n=l15, k=quad*8+j) ----
    const int qrow = qt*128 + wave*16 + l15;   // always < padded Lc (checked per ss)
    const float* qrp;
    if (qrow < ENC) qrp = eq + ((b*ENC + qrow)*H + head)*Dh;
    else            qrp = qv + (((b*SV + isum) + (qrow - ENC))*H + head)*Dh;
    bf16x8 qfrag[2];
    #pragma unroll
    for (int f = 0; f < 2; ++f) {
        const float* p = qrp + f*32 + quad*8;
        f32x4 a = *reinterpret_cast<const f32x4*>(p);
        f32x4 c = *reinterpret_cast<const f32x4*>(p + 4);
        uint4v u;
        u[0] = pack2bf(a[0]*qmul, a[1]*qmul);
        u[1] = pack2bf(a[2]*qmul, a[3]*qmul);
        u[2] = pack2bf(c[0]*qmul, c[1]*qmul);
        u[3] = pack2bf(c[2]*qmul, c[3]*qmul);
        qfrag[f] = __builtin_bit_cast(bf16x8, u);
    }

    f32x4 acc[4];                    // O^T: acc[dt] row d = dt*16+quad*4+reg, col q=l15
    #pragma unroll
    for (int dt = 0; dt < 4; ++dt) acc[dt] = {0.f,0.f,0.f,0.f};
    float m_s = -INFINITY, l_s = 0.f;   // per-lane scalars (q = l15)

    // staging roles: waves 0-3 stage K, waves 4-7 stage V (each thread 16 elems)
    const int t2  = tid & 255;
    const int klk = t2 >> 2;            // K: key row 0..63
    const int kd  = (t2 & 3) * 16;      // K: d base
    const int vk0 = (t2 & 15) * 4;      // V: key base (4 consecutive keys)
    const int vd0 = (t2 >> 4) * 4;      // V: d base (4 consecutive d)
    const bool krole = (tid < 256);     // wave-uniform (waves 0-3)

    // incremental staging pointers: enc covers exactly tiles 0,1 (ENC=128);
    // video tiles advance vidP by TILEF per tile.
    const float* encP;
    const float* vidP;
    if (krole) {
        encP = ek + ((size_t)(b*ENC + klk)*H + head)*Dh + kd;
        vidP = kv + ((size_t)((b*SV + isum) + klk)*H + head)*Dh + kd;
    } else {
        encP = ev + ((size_t)(b*ENC + vk0)*H + head)*Dh + vd0;
        vidP = vv + ((size_t)((b*SV + isum) + vk0)*H + head)*Dh + vd0;
    }

    f32x4 ld0, ld1, ld2, ld3;           // prefetch registers (live across compute)

    auto issue = [&](const float* base) {
        if (krole) {
            ld0 = *reinterpret_cast<const f32x4*>(base);
            ld1 = *reinterpret_cast<const f32x4*>(base + 4);
            ld2 = *reinterpret_cast<const f32x4*>(base + 8);
            ld3 = *reinterpret_cast<const f32x4*>(base + 12);
        } else {
            ld0 = *reinterpret_cast<const f32x4*>(base);
            ld1 = *reinterpret_cast<const f32x4*>(base + ROWF);
            ld2 = *reinterpret_cast<const f32x4*>(base + 2*ROWF);
            ld3 = *reinterpret_cast<const f32x4*>(base + 3*ROWF);
        }
    };

    auto write_tile = [&](short* kb, short* vb) {
        if (krole) {
            // K row-major bf16, 2x ds_write_b128
            uint4v kp;
            kp[0] = pack2bf(ld0[0], ld0[1]);
            kp[1] = pack2bf(ld0[2], ld0[3]);
            kp[2] = pack2bf(ld1[0], ld1[1]);
            kp[3] = pack2bf(ld1[2], ld1[3]);
            *reinterpret_cast<uint4v*>(&kb[klk*KS + kd]) = kp;
            kp[0] = pack2bf(ld2[0], ld2[1]);
            kp[1] = pack2bf(ld2[2], ld2[3]);
            kp[2] = pack2bf(ld3[0], ld3[1]);
            kp[3] = pack2bf(ld3[2], ld3[3]);
            *reinterpret_cast<uint4v*>(&kb[klk*KS + kd + 8]) = kp;
        } else {
            // V^T: register 4x4 transpose, 4x ds_write_b64
            #pragma unroll
            for (int j = 0; j < 4; ++j) {        // d = vd0 + j
                uint2v w;
                w[0] = pack2bf(ld0[j], ld1[j]);   // keys vk0, vk0+1
                w[1] = pack2bf(ld2[j], ld3[j]);   // keys vk0+2, vk0+3
                *reinterpret_cast<uint2v*>(&vb[(vd0 + j)*KS + vk0]) = w;
            }
        }
    };

    const int nkt = (seqlen + 63) >> 6;
    const bool active_q = (qt*128 + wave*16) < seqlen;   // wave-uniform
    const int src_base = l15 + ((quad & 1) << 5);        // bpermute source base lane

    issue(encP);

    for (int kt = 0; kt < nkt; ++kt) {
        short* kb = smem + (kt & 1) * (2*64*KS);
        short* vb = kb + 64*KS;

        write_tile(kb, vb);                 // compiler inserts vmcnt wait on ld*
        const int nx = kt + 1;
        if (nx < nkt) {
            if (nx == 1) issue(encP + TILEF);
            else { issue(vidP); vidP += TILEF; }
        }

        asm volatile("s_waitcnt lgkmcnt(0)" ::: "memory");  // our ds_writes visible
        __builtin_amdgcn_s_barrier();                        // NO vmcnt drain here
        __builtin_amdgcn_sched_barrier(0);

        if (!active_q) continue;

        const int rem  = seqlen - kt*64;
        const int nsub = (rem >= 64) ? 4 : (rem >> 4);   // seqlens are multiples of 16

        // ---- QK^T -> S^T: lane holds keys sub*16+quad*4+r for q=l15 ----
        float s[4][4];
        __builtin_amdgcn_s_setprio(1);
        #pragma unroll
        for (int sub = 0; sub < 4; ++sub) {
            if (sub < nsub) {
                const short* kr0 = &kb[(sub*16 + l15)*KS + quad*8];
                f32x4 sv = {0.f,0.f,0.f,0.f};
                sv = __builtin_amdgcn_mfma_f32_16x16x32_bf16(ldfrag(kr0),      qfrag[0], sv, 0,0,0);
                sv = __builtin_amdgcn_mfma_f32_16x16x32_bf16(ldfrag(kr0 + 32), qfrag[1], sv, 0,0,0);
                #pragma unroll
                for (int r = 0; r < 4; ++r) s[sub][r] = sv[r];
            } else {
                #pragma unroll
                for (int r = 0; r < 4; ++r) s[sub][r] = -INFINITY;
            }
        }
        __builtin_amdgcn_s_setprio(0);

        // ---- online softmax (per-lane scalar state, defer-max) ----
        float mx = s[0][0];
        #pragma unroll
        for (int sub = 0; sub < 4; ++sub)
            #pragma unroll
            for (int r = 0; r < 4; ++r) mx = fmaxf(mx, s[sub][r]);
        mx = fmaxf(mx, __shfl_xor(mx, 16, 64));
        mx = fmaxf(mx, __shfl_xor(mx, 32, 64));

        // rescale only when the wave's max grew by > 8 (log2 domain);
        // otherwise P <= 2^8, absorbed exactly at final normalization
        if (__ballot(mx > m_s + 8.f)) {
            const float mn = fmaxf(m_s, mx);
            const float alpha = __builtin_amdgcn_exp2f(m_s - mn);
            #pragma unroll
            for (int dt = 0; dt < 4; ++dt) acc[dt] *= alpha;
            l_s *= alpha;
            m_s = mn;
        }

        float rs = 0.f;
        unsigned pk[4][2];
        #pragma unroll
        for (int sub = 0; sub < 4; ++sub) {
            float p0 = __builtin_amdgcn_exp2f(s[sub][0] - m_s);
            float p1 = __builtin_amdgcn_exp2f(s[sub][1] - m_s);
            float p2 = __builtin_amdgcn_exp2f(s[sub][2] - m_s);
            float p3 = __builtin_amdgcn_exp2f(s[sub][3] - m_s);
            rs += (p0 + p1) + (p2 + p3);
            pk[sub][0] = pack2bf(p0, p1);
            pk[sub][1] = pack2bf(p2, p3);
        }
        rs += __shfl_xor(rs, 16, 64);
        rs += __shfl_xor(rs, 32, 64);
        l_s += rs;

        // ---- PV: O^T += V^T x P^T ; P^T B-frag via bpermute ----
        #pragma unroll
        for (int kstep = 0; kstep < 2; ++kstep) {
            if (kstep == 0 || nsub > 2) {
                uint4v pf;
                #pragma unroll
                for (int p = 0; p < 4; ++p) {
                    const int sl = src_base + ((p >> 1) << 4);
                    int va = __shfl((int)pk[kstep*2 + 0][p & 1], sl, 64);
                    int vb2 = __shfl((int)pk[kstep*2 + 1][p & 1], sl, 64);
                    pf[p] = (quad & 2) ? (unsigned)vb2 : (unsigned)va;
                }
                bf16x8 pfr = __builtin_bit_cast(bf16x8, pf);
                __builtin_amdgcn_s_setprio(1);
                #pragma unroll
                for (int dt = 0; dt < 4; ++dt) {
                    bf16x8 vfr = ldfrag(&vb[(dt*16 + l15)*KS + kstep*32 + quad*8]);
                    acc[dt] = __builtin_amdgcn_mfma_f32_16x16x32_bf16(vfr, pfr, acc[dt], 0,0,0);
                }
                __builtin_amdgcn_s_setprio(0);
            }
        }
    }

    // ---- epilogue: normalize, transpose via LDS (two 64-row passes), coalesced f32 store ----
    __syncthreads();                       // all waves done reading K/V buffers
    float* tbuf = reinterpret_cast<float*>(smem);   // [64][68] f32 = 17408 B
    const float inv = 1.0f / l_s;
    const int rowl = tid >> 3;             // 0..63
    const int colb = (tid & 7) * 8;        // 0..56
    #pragma unroll
    for (int p = 0; p < 2; ++p) {
        if (p) __syncthreads();            // previous pass's reads done before overwrite
        if ((wave >> 2) == p) {            // waves 0-3 own rows 0-63; waves 4-7 rows 64-127
            #pragma unroll
            for (int dt = 0; dt < 4; ++dt) {
                f32x4 t = acc[dt] * inv;
                *reinterpret_cast<f32x4*>(&tbuf[((wave & 3)*16 + l15)*68 + dt*16 + quad*4]) = t;
            }
        }
        __syncthreads();
        const int grow = qt*128 + p*64 + rowl;
        if (grow < seqlen) {
            float* orow = out + (size_t)(out_base + grow)*(H*Dh) + head*Dh + colb;
            const float* trow = tbuf + rowl*68 + colb;
            *reinterpret_cast<float4*>(orow)     = *reinterpret_cast<const float4*>(trow);
            *reinterpret_cast<float4*>(orow + 4) = *reinterpret_cast<const float4*>(trow + 4);
        }
    }
}

extern "C" void kernel_launch(void* const* d_in, const int* in_sizes, int n_in,
                              void* d_out, int out_size, void* d_ws, size_t ws_size,
                              hipStream_t stream) {
    const float* q     = (const float*)d_in[0];
    const float* k     = (const float*)d_in[1];
    const float* v     = (const float*)d_in[2];
    const float* eq    = (const float*)d_in[3];
    const float* ek    = (const float*)d_in[4];
    const float* ev    = (const float*)d_in[5];
    const float* scale = (const float*)d_in[11];
    float* out = (float*)d_out;

    vfa_kernel<<<dim3(768), dim3(512), 0, stream>>>(q, k, v, eq, ek, ev, scale, out);
}

// Round 5
// 211.574 us; speedup vs baseline: 1.2873x; 1.0181x over previous
//
#include <hip/hip_runtime.h>
#include <hip/hip_bf16.h>

typedef __attribute__((ext_vector_type(8))) __bf16 bf16x8;
typedef __attribute__((ext_vector_type(8))) short short8;
typedef __attribute__((ext_vector_type(4))) float f32x4;
typedef __attribute__((ext_vector_type(4))) unsigned int uint4v;
typedef __attribute__((ext_vector_type(2))) unsigned int uint2v;

#define KS 72
#define LOG2E 1.44269504088896340736f

// pack two fp32 -> two bf16 (lo in low short), round-half-up
__device__ __forceinline__ unsigned pack2bf(float lo, float hi) {
    unsigned a = __builtin_bit_cast(unsigned, lo) + 0x8000u;
    unsigned b = __builtin_bit_cast(unsigned, hi) + 0x8000u;
    return __builtin_amdgcn_perm(b, a, 0x07060302u);
}

__device__ __forceinline__ bf16x8 ldfrag(const short* p) {
    short8 s = *reinterpret_cast<const short8*>(p);
    return __builtin_bit_cast(bf16x8, s);
}

// S^T formulation: QK MFMA computes S^T[key][q] (A=K, B=Q); PV computes
// O^T[d][q] (A=V^T, B=P^T). Lane owns one q row (q = lane&15).
// R5: producer/consumer wave specialization.
//   waves 0-3 = consumers, each owns TWO 16-row q-groups (32 rows; tile=128):
//     K/V LDS fragments are wave-invariant, so each fragment is read ONCE
//     and feeds both groups' MFMAs -> LDS read traffic halves; the two
//     independent softmax chains give per-wave ILP.
//   waves 4-5 = K producers, waves 6-7 = V producers: load fp32, convert,
//     write buf[(t)&1] for tile t while consumers compute tile t-1. No
//     producer state lives across the barrier (no spill risk). One
//     s_barrier per tile: producer timeline W(0) B0 W(1) B1 W(2)...,
//     consumer B0 C(0) B1 C(1)...; W(t+2) reuses C(t)'s buffer and is
//     separated from it by B(t+1).  lgkmcnt(0) (producers) before barrier;
//     no vmcnt drain anywhere in the loop.
__global__ __launch_bounds__(512, 4) void vfa_kernel(
    const float* __restrict__ qv, const float* __restrict__ kv, const float* __restrict__ vv,
    const float* __restrict__ eq, const float* __restrict__ ek, const float* __restrict__ ev,
    const float* __restrict__ scale_p, float* __restrict__ out)
{
    constexpr int H = 16, Dh = 64, ENC = 128, SV = 1536;
    constexpr int ROWF = H*Dh;           // floats per token row = 1024
    constexpr int SS_CUM[9] = {0,144,272,384,480,560,640,704,768};
    constexpr int SEQL[8] = {1152,1008,864,720,640,560,480,400};
    constexpr int QTN[8]  = {9,8,7,6,5,5,4,4};          // ceil(seqlen/128)
    constexpr int OB[8]   = {2080,4096,3232,5104,0,1120,640,1680};
    constexpr int BB[8]   = {1,5,3,7,0,4,2,6};
    constexpr int ISUM[8] = {512,512,512,512,0,0,0,0};

    __shared__ __align__(16) short smem[4*64*KS];   // 2 x {K[64][KS] | V^T[64][KS]}

    const int bid = blockIdx.x;
    int ss = 0;
    #pragma unroll
    for (int i = 1; i < 8; ++i) ss += (bid >= SS_CUM[i]) ? 1 : 0;
    const int seqlen   = SEQL[ss];
    const int nqt      = QTN[ss];
    const int b        = BB[ss];
    const int isum     = ISUM[ss];
    const int out_base = OB[ss];
    const int local    = bid - SS_CUM[ss];
    const int head     = local / nqt;
    const int qt       = local - head * nqt;

    const int tid  = threadIdx.x;
    const int wave = tid >> 6;
    const int lane = tid & 63;
    const int quad = lane >> 4;
    const int l15  = lane & 15;
    const bool consumer = (wave < 4);

    const float qmul = scale_p[0] * LOG2E;

    // ---- consumer state: 2 q-groups per wave ----
    bf16x8 qfrag[2][2];                 // [group][frag]
    f32x4  acc[2][4];                   // [group][dt]
    float  m_s[2] = {-INFINITY, -INFINITY};
    float  l_s[2] = {0.f, 0.f};
    #pragma unroll
    for (int g = 0; g < 2; ++g)
        #pragma unroll
        for (int dt = 0; dt < 4; ++dt) acc[g][dt] = {0.f,0.f,0.f,0.f};

    if (consumer) {
        #pragma unroll
        for (int g = 0; g < 2; ++g) {
            const int qrow = qt*128 + wave*32 + g*16 + l15;   // < padded Lc always
            const float* qrp;
            if (qrow < ENC) qrp = eq + ((size_t)(b*ENC + qrow)*H + head)*Dh;
            else            qrp = qv + ((size_t)((b*SV + isum) + (qrow - ENC))*H + head)*Dh;
            #pragma unroll
            for (int f = 0; f < 2; ++f) {
                const float* p = qrp + f*32 + quad*8;
                f32x4 a = *reinterpret_cast<const f32x4*>(p);
                f32x4 c = *reinterpret_cast<const f32x4*>(p + 4);
                uint4v u;
                u[0] = pack2bf(a[0]*qmul, a[1]*qmul);
                u[1] = pack2bf(a[2]*qmul, a[3]*qmul);
                u[2] = pack2bf(c[0]*qmul, c[1]*qmul);
                u[3] = pack2bf(c[2]*qmul, c[3]*qmul);
                qfrag[g][f] = __builtin_bit_cast(bf16x8, u);
            }
        }
    }

    const int nkt = (seqlen + 63) >> 6;
    const int src_base = l15 + ((quad & 1) << 5);   // bpermute source base lane
    const int pidx = tid & 127;                     // producer lane id within role pair

    for (int kt = 0; kt < nkt; ++kt) {
        short* kb = smem + (kt & 1) * (2*64*KS);
        short* vb = kb + 64*KS;

        if (!consumer) {
            if (wave < 6) {
                // ---- K producer: 128 threads, thread = (row, 32-d half) ----
                const int prow = pidx & 63;
                const int pd0  = (pidx >> 6) * 32;
                const int kr = kt*64 + prow;
                const float* base = (kr < ENC)
                    ? ek + ((size_t)(b*ENC + kr)*H + head)*Dh + pd0
                    : kv + ((size_t)((b*SV + isum) + (kr - ENC))*H + head)*Dh + pd0;
                f32x4 pl[8];
                #pragma unroll
                for (int i = 0; i < 8; ++i)
                    pl[i] = *reinterpret_cast<const f32x4*>(base + 4*i);
                short* dst = &kb[prow*KS + pd0];
                #pragma unroll
                for (int m = 0; m < 4; ++m) {
                    uint4v w;
                    w[0] = pack2bf(pl[2*m][0],   pl[2*m][1]);
                    w[1] = pack2bf(pl[2*m][2],   pl[2*m][3]);
                    w[2] = pack2bf(pl[2*m+1][0], pl[2*m+1][1]);
                    w[3] = pack2bf(pl[2*m+1][2], pl[2*m+1][3]);
                    *reinterpret_cast<uint4v*>(dst + m*8) = w;
                }
            } else {
                // ---- V producer: 128 threads, thread = (4 keys, 8 d) block ----
                const int pk0 = (pidx & 15) * 4;
                const int pd0 = (pidx >> 4) * 8;
                const int kr = kt*64 + pk0;        // tile fully enc or fully video
                const float* base = (kr < ENC)
                    ? ev + ((size_t)(b*ENC + kr)*H + head)*Dh + pd0
                    : vv + ((size_t)((b*SV + isum) + (kr - ENC))*H + head)*Dh + pd0;
                f32x4 pl[8];
                #pragma unroll
                for (int r = 0; r < 4; ++r) {
                    pl[2*r]   = *reinterpret_cast<const f32x4*>(base + r*ROWF);
                    pl[2*r+1] = *reinterpret_cast<const f32x4*>(base + r*ROWF + 4);
                }
                #pragma unroll
                for (int j = 0; j < 4; ++j) {      // d = pd0 + j
                    uint2v w;
                    w[0] = pack2bf(pl[0][j], pl[2][j]);
                    w[1] = pack2bf(pl[4][j], pl[6][j]);
                    *reinterpret_cast<uint2v*>(&vb[(pd0 + j)*KS + pk0]) = w;
                }
                #pragma unroll
                for (int j = 0; j < 4; ++j) {      // d = pd0 + 4 + j
                    uint2v w;
                    w[0] = pack2bf(pl[1][j], pl[3][j]);
                    w[1] = pack2bf(pl[5][j], pl[7][j]);
                    *reinterpret_cast<uint2v*>(&vb[(pd0 + 4 + j)*KS + pk0]) = w;
                }
            }
            asm volatile("s_waitcnt lgkmcnt(0)" ::: "memory");  // our ds_writes visible
        }
        __builtin_amdgcn_s_barrier();
        __builtin_amdgcn_sched_barrier(0);

        if (consumer) {
            const int rem  = seqlen - kt*64;
            const int nsub = (rem >= 64) ? 4 : (rem >> 4);   // seqlens multiple of 16

            // ---- QK^T -> S^T, shared K fragments feed both groups ----
            f32x4 sv[2][4];
            const f32x4 ninf = {-INFINITY,-INFINITY,-INFINITY,-INFINITY};
            #pragma unroll
            for (int sub = 0; sub < 4; ++sub) {
                if (sub < nsub) {
                    const short* kr0 = &kb[(sub*16 + l15)*KS + quad*8];
                    bf16x8 kf0 = ldfrag(kr0);
                    bf16x8 kf1 = ldfrag(kr0 + 32);
                    #pragma unroll
                    for (int g = 0; g < 2; ++g) {
                        f32x4 t = {0.f,0.f,0.f,0.f};
                        t = __builtin_amdgcn_mfma_f32_16x16x32_bf16(kf0, qfrag[g][0], t, 0,0,0);
                        t = __builtin_amdgcn_mfma_f32_16x16x32_bf16(kf1, qfrag[g][1], t, 0,0,0);
                        sv[g][sub] = t;
                    }
                } else {
                    sv[0][sub] = ninf;
                    sv[1][sub] = ninf;
                }
            }

            // ---- online softmax per group (independent chains) ----
            unsigned pk[2][4][2];
            #pragma unroll
            for (int g = 0; g < 2; ++g) {
                float mx = sv[g][0][0];
                #pragma unroll
                for (int sub = 0; sub < 4; ++sub)
                    #pragma unroll
                    for (int r = 0; r < 4; ++r) mx = fmaxf(mx, sv[g][sub][r]);
                mx = fmaxf(mx, __shfl_xor(mx, 16, 64));
                mx = fmaxf(mx, __shfl_xor(mx, 32, 64));
                const float mn = fmaxf(m_s[g], mx);
                const float alpha = __builtin_amdgcn_exp2f(m_s[g] - mn);
                m_s[g] = mn;
                #pragma unroll
                for (int dt = 0; dt < 4; ++dt) acc[g][dt] *= alpha;

                float rs = 0.f;
                #pragma unroll
                for (int sub = 0; sub < 4; ++sub) {
                    float p0 = __builtin_amdgcn_exp2f(sv[g][sub][0] - mn);
                    float p1 = __builtin_amdgcn_exp2f(sv[g][sub][1] - mn);
                    float p2 = __builtin_amdgcn_exp2f(sv[g][sub][2] - mn);
                    float p3 = __builtin_amdgcn_exp2f(sv[g][sub][3] - mn);
                    rs += (p0 + p1) + (p2 + p3);
                    pk[g][sub][0] = pack2bf(p0, p1);
                    pk[g][sub][1] = pack2bf(p2, p3);
                }
                rs += __shfl_xor(rs, 16, 64);
                rs += __shfl_xor(rs, 32, 64);
                l_s[g] = l_s[g] * alpha + rs;
            }

            // ---- PV: shared V fragments feed both groups ----
            #pragma unroll
            for (int kstep = 0; kstep < 2; ++kstep) {
                if (kstep == 0 || nsub > 2) {
                    uint4v pfv[2];
                    #pragma unroll
                    for (int g = 0; g < 2; ++g)
                        #pragma unroll
                        for (int p = 0; p < 4; ++p) {
                            const int sl = src_base + ((p >> 1) << 4);
                            int va  = __shfl((int)pk[g][kstep*2 + 0][p & 1], sl, 64);
                            int vb2 = __shfl((int)pk[g][kstep*2 + 1][p & 1], sl, 64);
                            pfv[g][p] = (quad & 2) ? (unsigned)vb2 : (unsigned)va;
                        }
                    bf16x8 pfr0 = __builtin_bit_cast(bf16x8, pfv[0]);
                    bf16x8 pfr1 = __builtin_bit_cast(bf16x8, pfv[1]);
                    #pragma unroll
                    for (int dt = 0; dt < 4; ++dt) {
                        bf16x8 vfr = ldfrag(&vb[(dt*16 + l15)*KS + kstep*32 + quad*8]);
                        acc[0][dt] = __builtin_amdgcn_mfma_f32_16x16x32_bf16(vfr, pfr0, acc[0][dt], 0,0,0);
                        acc[1][dt] = __builtin_amdgcn_mfma_f32_16x16x32_bf16(vfr, pfr1, acc[1][dt], 0,0,0);
                    }
                }
            }
        }
    }

    // ---- epilogue: normalize, transpose via LDS (two 64-row passes), coalesced f32 store ----
    __syncthreads();                       // all consumers done; producers idle
    float* tbuf = reinterpret_cast<float*>(smem);   // [64][68] f32 = 17408 B
    const float inv0 = 1.0f / l_s[0];
    const float inv1 = 1.0f / l_s[1];
    const int rowl = tid >> 3;             // 0..63
    const int colb = (tid & 7) * 8;        // 0..56
    #pragma unroll
    for (int p = 0; p < 2; ++p) {
        if (p) __syncthreads();            // previous pass's reads done before overwrite
        if (consumer && (wave >> 1) == p) {   // waves 0-1: rows 0-63; waves 2-3: rows 64-127
            const int rbase = (wave & 1) * 32;
            #pragma unroll
            for (int dt = 0; dt < 4; ++dt) {
                f32x4 tA = acc[0][dt] * inv0;
                f32x4 tB = acc[1][dt] * inv1;
                *reinterpret_cast<f32x4*>(&tbuf[(rbase + l15)*68      + dt*16 + quad*4]) = tA;
                *reinterpret_cast<f32x4*>(&tbuf[(rbase + 16 + l15)*68 + dt*16 + quad*4]) = tB;
            }
        }
        __syncthreads();
        const int grow = qt*128 + p*64 + rowl;
        if (grow < seqlen) {
            float* orow = out + (size_t)(out_base + grow)*(H*Dh) + head*Dh + colb;
            const float* trow = tbuf + rowl*68 + colb;
            *reinterpret_cast<float4*>(orow)     = *reinterpret_cast<const float4*>(trow);
            *reinterpret_cast<float4*>(orow + 4) = *reinterpret_cast<const float4*>(trow + 4);
        }
    }
}

extern "C" void kernel_launch(void* const* d_in, const int* in_sizes, int n_in,
                              void* d_out, int out_size, void* d_ws, size_t ws_size,
                              hipStream_t stream) {
    const float* q     = (const float*)d_in[0];
    const float* k     = (const float*)d_in[1];
    const float* v     = (const float*)d_in[2];
    const float* eq    = (const float*)d_in[3];
    const float* ek    = (const float*)d_in[4];
    const float* ev    = (const float*)d_in[5];
    const float* scale = (const float*)d_in[11];
    float* out = (float*)d_out;

    vfa_kernel<<<dim3(768), dim3(512), 0, stream>>>(q, k, v, eq, ek, ev, scale, out);
}